// Round 12
// baseline (365.408 us; speedup 1.0000x reference)
//
#include <hip/hip_runtime.h>
#include <hip/hip_bf16.h>

#define NN 20000
#define EE 320000
#define IN 128
#define HID 64
#define OUTC 128
#define NH 3
#define NEG 0.15f
#define IN2 320
#define HO1 192   // NH*HID
#define HO2 384   // NH*OUTC
#define NB_SCAN 79  // ceil(NN/256)
#define GRIDM 313   // ceil(NN/64)

typedef __hip_bfloat16 bf16;
typedef __attribute__((ext_vector_type(8))) short short8;  // 8 bf16 = 4 VGPR (MFMA A/B frag)
typedef __attribute__((ext_vector_type(4))) float f32x4;   // MFMA C/D frag

__device__ __forceinline__ float bf2f(bf16 v) { return __bfloat162float(v); }
__device__ __forceinline__ bf16 f2bf(float v) { return __float2bfloat16(v); }
__device__ __forceinline__ float lrelu(float s) { return s > 0.f ? s : NEG * s; }
__device__ __forceinline__ float b2f(unsigned short u) {
    union { unsigned int i; float f; } c; c.i = ((unsigned int)u) << 16; return c.f;
}
__device__ __forceinline__ float b2f_lo(unsigned int d) { return b2f((unsigned short)(d & 0xffffu)); }
__device__ __forceinline__ float b2f_hi(unsigned int d) { return b2f((unsigned short)(d >> 16)); }

// ---------------- CSR build (by dst) — proven rounds 4/7/8/10/11 ----------------
__global__ void k_count(const int* __restrict__ ei, int* __restrict__ cnt) {
    const int e = blockIdx.x * 256 + threadIdx.x;
    if (e < EE) atomicAdd(&cnt[ei[EE + e]], 1);
}

__global__ void k_scanA(const int* __restrict__ cnt, int* __restrict__ loc,
                        int* __restrict__ bsum) {
    __shared__ int sh[256];
    const int t = threadIdx.x;
    const int i = blockIdx.x * 256 + t;
    const int v = (i < NN) ? cnt[i] : 0;
    sh[t] = v; __syncthreads();
    for (int off = 1; off < 256; off <<= 1) {
        const int add = (t >= off) ? sh[t - off] : 0;
        __syncthreads();
        sh[t] += add; __syncthreads();
    }
    if (i < NN) loc[i] = sh[t];
    if (t == 255) bsum[blockIdx.x] = sh[255];
}

__global__ void k_scanB(int* __restrict__ bsum) {
    __shared__ int sh[128];
    const int t = threadIdx.x;
    const int v = (t < NB_SCAN) ? bsum[t] : 0;
    sh[t] = v; __syncthreads();
    for (int off = 1; off < 128; off <<= 1) {
        const int add = (t >= off) ? sh[t - off] : 0;
        __syncthreads();
        sh[t] += add; __syncthreads();
    }
    if (t < NB_SCAN) bsum[t] = sh[t] - v;
}

__global__ void k_scanC(const int* __restrict__ loc, const int* __restrict__ cnt,
                        const int* __restrict__ bsum, int* __restrict__ row_off,
                        int* __restrict__ fill) {
    const int i = blockIdx.x * 256 + threadIdx.x;
    if (i < NN) {
        const int ro = loc[i] - cnt[i] + bsum[blockIdx.x];
        row_off[i] = ro; fill[i] = ro;
    }
    if (i == 0) row_off[NN] = EE;
}

__global__ void k_scatter(const int* __restrict__ ei, int* __restrict__ fill,
                          int* __restrict__ csr_src) {
    const int e = blockIdx.x * 256 + threadIdx.x;
    if (e < EE) {
        const int p = atomicAdd(&fill[ei[EE + e]], 1);
        csr_src[p] = ei[e];
    }
}

// ---------------- pre-pass: bf16 casts / weight transpose ----------------
__global__ void k_a2x(const float* __restrict__ x, bf16* __restrict__ xb) {
    const int idx = blockIdx.x * 256 + threadIdx.x;
    if (idx < NN * IN) xb[idx] = f2bf(x[idx]);
}

// Wt[n][k] = bf16( n<NO ? Wl[k][n] : Wr[k][n-NO] ), Wl/Wr [K,NO] row stride NO
__global__ void k_wt(const float* __restrict__ Wl, const float* __restrict__ Wr,
                     int K, int NO, bf16* __restrict__ Wt) {
    const int idx = blockIdx.x * 256 + threadIdx.x;
    if (idx >= 2 * NO * K) return;
    const int n = idx / K, k = idx - n * K;
    const float* W = (n < NO) ? Wl : Wr;
    const int nn = (n < NO) ? n : n - NO;
    Wt[idx] = f2bf(W[(size_t)k * NO + nn]);
}

// ---------------- MFMA GEMM: 32x64/wave, prefetch; head-interleaved epilogue ----
// Output layout: element offset (row*CH + c)*PW + h  where col = h*CH + c within l/r.
// Layer 1: CH=64, PW=4 (pad).  Layer 2: CH=128, PW=3.
template <int K, int CH, int PW>
__launch_bounds__(256)
__global__ void gemm_mfma(const bf16* __restrict__ A0, int As0,   // k < 128
                          const bf16* __restrict__ A1, int As1,   // k >= 128 (index k-128)
                          const bf16* __restrict__ Wt,
                          const float* __restrict__ bl, const float* __restrict__ br,
                          int NO, bf16* __restrict__ outl, bf16* __restrict__ outr) {
    const int w = threadIdx.x >> 6;
    const int lane = threadIdx.x & 63;
    const int quad = lane >> 4, l15 = lane & 15;
    const int m0 = blockIdx.x * 64 + (w >> 1) * 32;
    const int n0 = blockIdx.y * 128 + (w & 1) * 64;

    int am0 = m0 + l15;      if (am0 >= NN) am0 = NN - 1;   // clamp: loads stay in ws
    int am1 = m0 + 16 + l15; if (am1 >= NN) am1 = NN - 1;
    const bf16* wp = Wt + (size_t)(n0 + l15) * K + quad * 8;

    f32x4 acc[2][4];
#pragma unroll
    for (int nt = 0; nt < 4; ++nt) {
        const int col = n0 + nt * 16 + l15;
        const float b = (col < NO) ? bl[col] : br[col - NO];
        acc[0][nt] = (f32x4){b, b, b, b};
        acc[1][nt] = (f32x4){b, b, b, b};
    }

    short8 ca0, ca1, cb[4];
    {
        ca0 = *(const short8*)(A0 + (size_t)am0 * As0 + quad * 8);
        ca1 = *(const short8*)(A0 + (size_t)am1 * As0 + quad * 8);
#pragma unroll
        for (int nt = 0; nt < 4; ++nt)
            cb[nt] = *(const short8*)(wp + (size_t)nt * 16 * K);
    }

#pragma unroll
    for (int ks = 0; ks < K; ks += 32) {
        short8 na0 = {}, na1 = {}, nb[4] = {};
        if (ks + 32 < K) {
            const int nks = ks + 32;
            const bf16* a0p = (K <= 128 || nks < 128)
                ? (A0 + (size_t)am0 * As0 + nks) : (A1 + (size_t)am0 * As1 + (nks - 128));
            const bf16* a1p = (K <= 128 || nks < 128)
                ? (A0 + (size_t)am1 * As0 + nks) : (A1 + (size_t)am1 * As1 + (nks - 128));
            na0 = *(const short8*)(a0p + quad * 8);
            na1 = *(const short8*)(a1p + quad * 8);
#pragma unroll
            for (int nt = 0; nt < 4; ++nt)
                nb[nt] = *(const short8*)(wp + (size_t)nt * 16 * K + nks);
        }
#pragma unroll
        for (int nt = 0; nt < 4; ++nt) {
            acc[0][nt] = __builtin_amdgcn_mfma_f32_16x16x32_bf16(ca0, cb[nt], acc[0][nt], 0, 0, 0);
            acc[1][nt] = __builtin_amdgcn_mfma_f32_16x16x32_bf16(ca1, cb[nt], acc[1][nt], 0, 0, 0);
        }
        ca0 = na0; ca1 = na1;
#pragma unroll
        for (int nt = 0; nt < 4; ++nt) cb[nt] = nb[nt];
    }

#pragma unroll
    for (int mt = 0; mt < 2; ++mt)
#pragma unroll
    for (int nt = 0; nt < 4; ++nt) {
        const int col = n0 + nt * 16 + l15;
        const int cc = (col < NO) ? col : col - NO;
        bf16* o = (col < NO) ? outl : outr;
        const int h = cc / CH, c = cc - h * CH;
#pragma unroll
        for (int r = 0; r < 4; ++r) {
            const int row = m0 + mt * 16 + quad * 4 + r;
            if (row < NN) o[((size_t)row * CH + c) * PW + h] = f2bf(acc[mt][nt][r]);
        }
    }
}

// ---------------- gather1: permuted loads (1 dwordx2/edge), 4-edge unroll ------
// xl/xr layout [N][64][4] bf16: lane's 3 head values contiguous at (i*64+lane)*4.
__global__ void gather1(const int* __restrict__ row_off, const int* __restrict__ csr_src,
                        const bf16* __restrict__ xl, const bf16* __restrict__ xr,
                        const float* __restrict__ att, const float* __restrict__ bias,
                        bf16* __restrict__ h1) {
    const int i = (blockIdx.x * blockDim.x + threadIdx.x) >> 6;
    const int lane = threadIdx.x & 63;
    if (i >= NN) return;
    const unsigned short* xlu = (const unsigned short*)xl;
    const ushort4 rvu = *(const ushort4*)((const unsigned short*)xr + (size_t)i * 256 + lane * 4);
    const float rv0 = b2f(rvu.x), rv1 = b2f(rvu.y), rv2 = b2f(rvu.z);
    const float av0 = att[lane], av1 = att[64 + lane], av2 = att[128 + lane];
    int k = row_off[i];
    const int e = row_off[i + 1];
    float a0 = 0.f, a1 = 0.f, a2 = 0.f, d0 = 0.f, d1 = 0.f, d2 = 0.f;
    while (k < e) {
        const int batch = min(64, e - k);
        const int jv = (lane < batch) ? csr_src[k + lane] : 0;
        int m = 0;
        for (; m + 4 <= batch; m += 4) {           // 4 edges x 3 heads = 12 chains
            int j[4];
#pragma unroll
            for (int q = 0; q < 4; ++q) j[q] = __shfl(jv, m + q, 64);
            float lv[4][3], p[4][3];
#pragma unroll
            for (int q = 0; q < 4; ++q) {
                const ushort4 u = *(const ushort4*)(xlu + (size_t)j[q] * 256 + lane * 4);
                lv[q][0] = b2f(u.x); lv[q][1] = b2f(u.y); lv[q][2] = b2f(u.z);
                p[q][0] = lrelu(lv[q][0] + rv0) * av0;
                p[q][1] = lrelu(lv[q][1] + rv1) * av1;
                p[q][2] = lrelu(lv[q][2] + rv2) * av2;
            }
#pragma unroll
            for (int off = 32; off > 0; off >>= 1)
#pragma unroll
                for (int q = 0; q < 4; ++q) {
                    p[q][0] += __shfl_xor(p[q][0], off, 64);
                    p[q][1] += __shfl_xor(p[q][1], off, 64);
                    p[q][2] += __shfl_xor(p[q][2], off, 64);
                }
#pragma unroll
            for (int q = 0; q < 4; ++q) {
                const float e0 = __expf(p[q][0]), e1 = __expf(p[q][1]), e2 = __expf(p[q][2]);
                a0 += e0 * lv[q][0]; d0 += e0;
                a1 += e1 * lv[q][1]; d1 += e1;
                a2 += e2 * lv[q][2]; d2 += e2;
            }
        }
        for (; m < batch; ++m) {                   // tail (<=3 edges)
            const int j = __shfl(jv, m, 64);
            const ushort4 u = *(const ushort4*)(xlu + (size_t)j * 256 + lane * 4);
            const float l0 = b2f(u.x), l1 = b2f(u.y), l2 = b2f(u.z);
            float p0 = lrelu(l0 + rv0) * av0;
            float p1 = lrelu(l1 + rv1) * av1;
            float p2 = lrelu(l2 + rv2) * av2;
#pragma unroll
            for (int off = 32; off > 0; off >>= 1) {
                p0 += __shfl_xor(p0, off, 64);
                p1 += __shfl_xor(p1, off, 64);
                p2 += __shfl_xor(p2, off, 64);
            }
            const float e0 = __expf(p0), e1 = __expf(p1), e2 = __expf(p2);
            a0 += e0 * l0; d0 += e0;
            a1 += e1 * l1; d1 += e1;
            a2 += e2 * l2; d2 += e2;
        }
        k += batch;
    }
    const float o0 = a0 / (d0 + 1e-16f) + bias[lane];
    const float o1 = a1 / (d1 + 1e-16f) + bias[64 + lane];
    const float o2 = a2 / (d2 + 1e-16f) + bias[128 + lane];
    h1[(size_t)i * HO1 + lane]       = f2bf(o0 > 0.f ? o0 : 0.f);
    h1[(size_t)i * HO1 + 64 + lane]  = f2bf(o1 > 0.f ? o1 : 0.f);
    h1[(size_t)i * HO1 + 128 + lane] = f2bf(o2 > 0.f ? o2 : 0.f);
}

// ---------------- gather2: permuted loads (3 dwords/edge), 4-edge unroll -------
// xl2/xr2 layout [N][128][3] bf16: lane's 6 values (c=2l,2l+1 x 3 heads) at
// element (i*128 + 2*lane)*3 = i*384 + 6*lane -> 3 aligned dwords.
// lv convention: lv[2h+c'] ; dword mapping: d0=(c0h0,c0h1) d1=(c0h2,c1h0) d2=(c1h1,c1h2)
__global__ void gather2(const int* __restrict__ row_off, const int* __restrict__ csr_src,
                        const bf16* __restrict__ xl2, const bf16* __restrict__ xr2,
                        const float* __restrict__ att2, const float* __restrict__ bias2,
                        float* __restrict__ out) {
    const int i = (blockIdx.x * blockDim.x + threadIdx.x) >> 6;
    const int lane = threadIdx.x & 63;
    if (i >= NN) return;
    const unsigned int* xlw = (const unsigned int*)xl2;
    const unsigned int* xrw = (const unsigned int*)xr2;
    float rv[6], av[6];
    {
        const size_t rb = (size_t)i * 192 + 3 * lane;   // dword index
        const unsigned int r0 = xrw[rb], r1 = xrw[rb + 1], r2 = xrw[rb + 2];
        rv[0] = b2f_lo(r0); rv[2] = b2f_hi(r0);
        rv[4] = b2f_lo(r1); rv[1] = b2f_hi(r1);
        rv[3] = b2f_lo(r2); rv[5] = b2f_hi(r2);
#pragma unroll
        for (int h = 0; h < NH; ++h) {
            const float2 a2 = *(const float2*)&att2[h * OUTC + 2 * lane];
            av[2 * h] = a2.x; av[2 * h + 1] = a2.y;
        }
    }
    float acc[6] = {0.f, 0.f, 0.f, 0.f, 0.f, 0.f};
    float den[3] = {0.f, 0.f, 0.f};
    int k = row_off[i];
    const int e = row_off[i + 1];
    while (k < e) {
        const int batch = min(64, e - k);
        const int jv = (lane < batch) ? csr_src[k + lane] : 0;
        int m = 0;
        for (; m + 4 <= batch; m += 4) {           // 4 edges x 3 heads = 12 chains
            int j[4];
#pragma unroll
            for (int q = 0; q < 4; ++q) j[q] = __shfl(jv, m + q, 64);
            float lv[4][6], p[4][3];
#pragma unroll
            for (int q = 0; q < 4; ++q) {
                const size_t b = (size_t)j[q] * 192 + 3 * lane;
                const unsigned int d0 = xlw[b], d1 = xlw[b + 1], d2 = xlw[b + 2];
                lv[q][0] = b2f_lo(d0); lv[q][2] = b2f_hi(d0);
                lv[q][4] = b2f_lo(d1); lv[q][1] = b2f_hi(d1);
                lv[q][3] = b2f_lo(d2); lv[q][5] = b2f_hi(d2);
#pragma unroll
                for (int h = 0; h < NH; ++h)
                    p[q][h] = lrelu(lv[q][2 * h] + rv[2 * h]) * av[2 * h]
                            + lrelu(lv[q][2 * h + 1] + rv[2 * h + 1]) * av[2 * h + 1];
            }
#pragma unroll
            for (int off = 32; off > 0; off >>= 1)
#pragma unroll
                for (int q = 0; q < 4; ++q) {
                    p[q][0] += __shfl_xor(p[q][0], off, 64);
                    p[q][1] += __shfl_xor(p[q][1], off, 64);
                    p[q][2] += __shfl_xor(p[q][2], off, 64);
                }
#pragma unroll
            for (int q = 0; q < 4; ++q) {
#pragma unroll
                for (int h = 0; h < NH; ++h) {
                    const float ex = __expf(p[q][h]);
                    acc[2 * h]     += ex * lv[q][2 * h];
                    acc[2 * h + 1] += ex * lv[q][2 * h + 1];
                    den[h] += ex;
                }
            }
        }
        for (; m < batch; ++m) {                   // tail (<=3 edges)
            const int j = __shfl(jv, m, 64);
            const size_t b = (size_t)j * 192 + 3 * lane;
            const unsigned int d0 = xlw[b], d1 = xlw[b + 1], d2 = xlw[b + 2];
            float lv[6];
            lv[0] = b2f_lo(d0); lv[2] = b2f_hi(d0);
            lv[4] = b2f_lo(d1); lv[1] = b2f_hi(d1);
            lv[3] = b2f_lo(d2); lv[5] = b2f_hi(d2);
            float p[3];
#pragma unroll
            for (int h = 0; h < NH; ++h)
                p[h] = lrelu(lv[2 * h] + rv[2 * h]) * av[2 * h]
                     + lrelu(lv[2 * h + 1] + rv[2 * h + 1]) * av[2 * h + 1];
#pragma unroll
            for (int off = 32; off > 0; off >>= 1) {
                p[0] += __shfl_xor(p[0], off, 64);
                p[1] += __shfl_xor(p[1], off, 64);
                p[2] += __shfl_xor(p[2], off, 64);
            }
#pragma unroll
            for (int h = 0; h < NH; ++h) {
                const float ex = __expf(p[h]);
                acc[2 * h]     += ex * lv[2 * h];
                acc[2 * h + 1] += ex * lv[2 * h + 1];
                den[h] += ex;
            }
        }
        k += batch;
    }
    const float i0 = 1.f / (den[0] + 1e-16f);
    const float i1 = 1.f / (den[1] + 1e-16f);
    const float i2 = 1.f / (den[2] + 1e-16f);
    const float2 b2 = *(const float2*)&bias2[2 * lane];
    float v0 = (acc[0] * i0 + acc[2] * i1 + acc[4] * i2) * (1.f / 3.f) + b2.x;
    float v1 = (acc[1] * i0 + acc[3] * i1 + acc[5] * i2) * (1.f / 3.f) + b2.y;
    v0 = v0 > 0.f ? v0 : 0.f;
    v1 = v1 > 0.f ? v1 : 0.f;
    *(float2*)&out[(size_t)i * OUTC + 2 * lane] = make_float2(v0, v1);
}

extern "C" void kernel_launch(void* const* d_in, const int* in_sizes, int n_in,
                              void* d_out, int out_size, void* d_ws, size_t ws_size,
                              hipStream_t stream) {
    const float* x    = (const float*)d_in[0];
    const float* Wl1  = (const float*)d_in[1];
    const float* bl1  = (const float*)d_in[2];
    const float* Wr1  = (const float*)d_in[3];
    const float* br1  = (const float*)d_in[4];
    const float* att1 = (const float*)d_in[5];
    const float* bias1= (const float*)d_in[6];
    const float* Wl2  = (const float*)d_in[7];
    const float* bl2  = (const float*)d_in[8];
    const float* Wr2  = (const float*)d_in[9];
    const float* br2  = (const float*)d_in[10];
    const float* att2 = (const float*)d_in[11];
    const float* bias2= (const float*)d_in[12];
    const int*   ei   = (const int*)d_in[13];

    char* ws = (char*)d_ws;
    // Pool layout (bytes), peak 45,713,936 — identical to proven rounds 10/11:
    //  [0,         5,120,000)  xb   bf16 [N,128]
    //  [5.12e6,   12,800,000)  h1b  bf16 [N,192]
    //  [12.8e6,   23,040,000)  xl1p bf16 [N][64][4]  \ dead after gather1 ->
    //  [23.04e6,  33,280,000)  xr1p bf16 [N][64][4]  /  xl2p [N][128][3] = [12.8e6, 28.16e6)
    //  [28.16e6,  43,520,000)  xr2p bf16 [N][128][3] (aliases xr1p tail, written after gather1)
    //  [43.52e6,  45,124,104)  CSR: cnt/fill/loc/bsum/rowoff/csrsrc
    //  [45,124,112, 45,222,416)  Wt1 bf16 [384][128]
    //  [45,222,416, 45,713,936)  Wt2 bf16 [768][320]
    bf16*  xb     = (bf16*)(ws);
    bf16*  h1b    = (bf16*)(ws + 5120000);
    bf16*  xl1p   = (bf16*)(ws + 12800000);
    bf16*  xr1p   = (bf16*)(ws + 23040000);
    bf16*  xl2p   = (bf16*)(ws + 12800000);   // alias: xl1p/xr1p dead after gather1
    bf16*  xr2p   = (bf16*)(ws + 28160000);
    int*   cnt    = (int*)(ws + 43520000);
    int*   fill   = (int*)(ws + 43600000);
    int*   loc    = (int*)(ws + 43680000);
    int*   bsum   = (int*)(ws + 43760000);
    int*   rowoff = (int*)(ws + 43764096);
    int*   csrsrc = (int*)(ws + 43844104);    // +1,280,000 -> 45,124,104
    bf16*  Wt1    = (bf16*)(ws + 45124112);
    bf16*  Wt2    = (bf16*)(ws + 45222416);

    // ---- pre-pass: casts + weight transposes ----
    k_a2x<<<(NN * IN + 255) / 256, 256, 0, stream>>>(x, xb);
    k_wt<<<(HO2 * IN + 255) / 256, 256, 0, stream>>>(Wl1, Wr1, IN, HO1, Wt1);      // 384x128
    k_wt<<<(2 * HO2 * IN2 + 255) / 256, 256, 0, stream>>>(Wl2, Wr2, IN2, HO2, Wt2); // 768x320

    // ---- CSR build (shared by both layers) ----
    hipMemsetAsync(cnt, 0, NN * sizeof(int), stream);
    k_count<<<(EE + 255) / 256, 256, 0, stream>>>(ei, cnt);
    k_scanA<<<NB_SCAN, 256, 0, stream>>>(cnt, loc, bsum);
    k_scanB<<<1, 128, 0, stream>>>(bsum);
    k_scanC<<<NB_SCAN, 256, 0, stream>>>(loc, cnt, bsum, rowoff, fill);
    k_scatter<<<(EE + 255) / 256, 256, 0, stream>>>(ei, fill, csrsrc);

    // ---- layer 1 ----
    gemm_mfma<IN, HID, 4><<<dim3(GRIDM, HO2 / 128), 256, 0, stream>>>(
        xb, IN, (const bf16*)nullptr, 0, Wt1, bl1, br1, HO1, xl1p, xr1p);
    gather1<<<NN / 4, 256, 0, stream>>>(rowoff, csrsrc, xl1p, xr1p, att1, bias1, h1b);

    // ---- layer 2 ----
    gemm_mfma<IN2, OUTC, 3><<<dim3(GRIDM, 2 * HO2 / 128), 256, 0, stream>>>(
        xb, IN, h1b, HO1, Wt2, bl2, br2, HO2, xl2p, xr2p);
    gather2<<<NN / 4, 256, 0, stream>>>(rowoff, csrsrc, xl2p, xr2p, att2, bias2,
                                        (float*)d_out);
}